// Round 15
// baseline (142.002 us; speedup 1.0000x reference)
//
#include <hip/hip_runtime.h>
#include <cstdint>
#include <cstddef>

// B=2, S=1024, D=512, NH=16 (chunk width), C=32 chunks.
// weights (C,B,S,S) fp32 = 256 MiB written once (fused, never re-read).
// out_pre scramble: (c,b,m,h) -> [c>>4][(c&15)*64 + (m>>4)][(m&15)*32 + b*16 + h]

typedef __attribute__((ext_vector_type(8)))  short    short8;   // 8 bf16 (4 VGPR)
typedef __attribute__((ext_vector_type(4)))  float    f32x4;    // 16x16 MFMA C/D
typedef __attribute__((ext_vector_type(4)))  unsigned u32x4;

union FragU { u32x4 u; short8 s; };

// bf16 round-to-nearest-even pack of two floats into one u32 (lo=a, hi=b)
__device__ __forceinline__ unsigned pk_bf16(float a, float b) {
    unsigned ua = __float_as_uint(a), ub = __float_as_uint(b);
    ua = (ua + 0x7fffu + ((ua >> 16) & 1u)) >> 16;
    ub = (ub + 0x7fffu + ((ub >> 16) & 1u)) >> 16;
    return ua | (ub << 16);
}

// ---------------------------------------------------------------------------
// MFMA NT GEMM v2: P[M][512] = bf16(X) * bf16(W)^T, tile 128m x 64n.
// R14 rebalance: wave owns 32 rows x 64 cols = 2 A-frags + 4 B-frags ->
// 6 ds_read_b128 per 8 MFMA (R13 body was 5 reads per 4 MFMA; 40% fewer
// LDS reads per unit work, which was the bound). 4 K-stages of 128.
// Fragment discipline unchanged (verified R12/R13): A row=lane&15,
// k=(lane>>4)*8+idx; B identical; D col=lane&15, row=(lane>>4)*4+reg.
// LDS: Xs[128][17][4] 34KB + Ws[64][17][4] 17KB = 51KB -> 2 blocks/CU.
// VGPR ~90 < 128 cap (launch_bounds(256,2) per ledger) -> no spill.
// ---------------------------------------------------------------------------
__device__ __forceinline__ void gemm_nt_mfma_body(const float* __restrict__ X,
                                                  const float* __restrict__ W,
                                                  float* __restrict__ P)
{
    __shared__ unsigned Xs[128 * 17 * 4];  // 34 KB
    __shared__ unsigned Ws[64 * 17 * 4];   // 17 KB
    const int t  = threadIdx.x;
    const int m0 = blockIdx.y << 7;        // 128-row tile
    const int n0 = blockIdx.x << 6;        // 64-col tile
    const int wave = t >> 6, lane = t & 63;
    const int ml = lane & 15;              // A row / B col within 16
    const int g  = lane >> 4;              // k-group (0..3)

    f32x4 acc[2][4] = {{{0,0,0,0},{0,0,0,0},{0,0,0,0},{0,0,0,0}},
                       {{0,0,0,0},{0,0,0,0},{0,0,0,0},{0,0,0,0}}};

#pragma unroll 1
    for (int st = 0; st < 4; ++st) {
        if (st) __syncthreads();           // prior compute done before restage
        // ---- stage X: 128 rows x 16 kf (kf fastest; 8 reps) ----
#pragma unroll
        for (int rep = 0; rep < 8; ++rep) {
            int f  = rep * 256 + t;
            int kf = f & 15, r = f >> 4;
            const float* xr = X + (size_t)(m0 + r) * 512 + st * 128 + kf * 8;
            float4 a = *(const float4*)xr;
            float4 b = *(const float4*)(xr + 4);
            unsigned* dx = &Xs[(r * 17 + kf) * 4];
            dx[0] = pk_bf16(a.x, a.y); dx[1] = pk_bf16(a.z, a.w);
            dx[2] = pk_bf16(b.x, b.y); dx[3] = pk_bf16(b.z, b.w);
        }
        // ---- stage W: 64 rows x 16 kf (4 reps) ----
#pragma unroll
        for (int rep = 0; rep < 4; ++rep) {
            int f  = rep * 256 + t;
            int kf = f & 15, r = f >> 4;
            const float* wr = W + (size_t)(n0 + r) * 512 + st * 128 + kf * 8;
            float4 c = *(const float4*)wr;
            float4 d = *(const float4*)(wr + 4);
            unsigned* dw = &Ws[(r * 17 + kf) * 4];
            dw[0] = pk_bf16(c.x, c.y); dw[1] = pk_bf16(c.z, c.w);
            dw[2] = pk_bf16(d.x, d.y); dw[3] = pk_bf16(d.z, d.w);
        }
        __syncthreads();
        // ---- compute: 4 k-steps of 32 ----
#pragma unroll
        for (int ks = 0; ks < 4; ++ks) {
            const int kf = ks * 4 + g;
            FragU a0, a1;
            a0.u = *(const u32x4*)&Xs[((wave * 32 + ml) * 17 + kf) * 4];
            a1.u = *(const u32x4*)&Xs[((wave * 32 + 16 + ml) * 17 + kf) * 4];
#pragma unroll
            for (int nf = 0; nf < 4; ++nf) {
                FragU bw;
                bw.u = *(const u32x4*)&Ws[((nf * 16 + ml) * 17 + kf) * 4];
                acc[0][nf] = __builtin_amdgcn_mfma_f32_16x16x32_bf16(
                    a0.s, bw.s, acc[0][nf], 0, 0, 0);
                acc[1][nf] = __builtin_amdgcn_mfma_f32_16x16x32_bf16(
                    a1.s, bw.s, acc[1][nf], 0, 0, 0);
            }
        }
    }
    // ---- store: row = wave*32 + af*16 + g*4 + r, col = nf*16 + ml ----
#pragma unroll
    for (int af = 0; af < 2; ++af)
#pragma unroll
        for (int nf = 0; nf < 4; ++nf)
#pragma unroll
            for (int r = 0; r < 4; ++r) {
                const int m = m0 + wave * 32 + af * 16 + g * 4 + r;
                P[(size_t)m * 512 + n0 + nf * 16 + ml] = acc[af][nf][r];
            }
}

__global__ __launch_bounds__(256, 2) void proj3_kernel(
    const float* __restrict__ Q, const float* __restrict__ K, const float* __restrict__ V,
    const float* __restrict__ Wq, const float* __restrict__ Wk, const float* __restrict__ Wv,
    float* __restrict__ q, float* __restrict__ k, float* __restrict__ v)
{
    const float* X; const float* W; float* P;
    if (blockIdx.z == 0)      { X = Q; W = Wq; P = q; }
    else if (blockIdx.z == 1) { X = K; W = Wk; P = k; }
    else                      { X = V; W = Wv; P = v; }
    gemm_nt_mfma_body(X, W, P);
}

__global__ __launch_bounds__(256, 2) void outproj_kernel(
    const float* __restrict__ att, const float* __restrict__ Wo, float* __restrict__ out)
{
    gemm_nt_mfma_body(att, Wo, out);
}

// ---------------------------------------------------------------------------
// v12 MFMA attention (R14: PASSED, 8 waves, LDS 73.1KB -> 2 blocks/CU ->
// 4 waves/SIMD). Unchanged except: weights stores are now NONTEMPORAL
// (268 MB streamed write, never re-read -> bypass L2, keep q/k/v/att hot).
// ---------------------------------------------------------------------------
__global__ __launch_bounds__(512)
void attn_mfma_kernel(
    const float* __restrict__ q, const float* __restrict__ k, const float* __restrict__ v,
    float* __restrict__ wts, float* __restrict__ att)
{
    __shared__ unsigned ksF[64 * 128];    // [nt][(n&15)+16g][4] bf16-pair frags
    __shared__ unsigned vsT[16][514];     // [h][n-pair] bf16x2 (+pad, 0-conflict)
    __shared__ unsigned pbuf[8][16][18];  // per-wave P tile [m][n-pair], padded

    const int t     = threadIdx.x;
    const int bid   = blockIdx.x;         // 512 blocks
    const int strip = bid & 7;            // 8 strips of 128 m-rows
    const int cb    = bid >> 3;           // c*2 + b
    const int b     = cb & 1;
    const int c     = cb >> 1;
    const int m0b   = strip << 7;

    const float* kb = k + (size_t)b * 524288 + c * 16;
    const float* vb = v + (size_t)b * 524288 + c * 16;

    // ---- stage K as A-fragments: tasks (n 0..1023, g 0..1) ----
#pragma unroll
    for (int rep = 0; rep < 4; ++rep) {
        int f = rep * 512 + t;            // 0..2047
        int n = f >> 1, gg = f & 1;
        const float* kr = kb + (size_t)n * 512 + gg * 8;
        float4 a  = *(const float4*)kr;
        float4 bq = *(const float4*)(kr + 4);
        unsigned* dst = &ksF[(n >> 4) * 128 + ((n & 15) + (gg << 4)) * 4];
        dst[0] = pk_bf16(a.x, a.y);
        dst[1] = pk_bf16(a.z, a.w);
        dst[2] = pk_bf16(bq.x, bq.y);
        dst[3] = pk_bf16(bq.z, bq.w);
    }
    // ---- stage V as [h][n-pair] bf16 pairs ----
#pragma unroll
    for (int rep = 0; rep < 4; ++rep) {
        int f = rep * 512 + t;            // p(0..511) x hq(0..3)
        int p = f >> 2, hq = f & 3;
        float4 v0 = *(const float4*)(vb + (size_t)(2 * p)     * 512 + hq * 4);
        float4 v1 = *(const float4*)(vb + (size_t)(2 * p + 1) * 512 + hq * 4);
        vsT[hq * 4 + 0][p] = pk_bf16(v0.x, v1.x);
        vsT[hq * 4 + 1][p] = pk_bf16(v0.y, v1.y);
        vsT[hq * 4 + 2][p] = pk_bf16(v0.z, v1.z);
        vsT[hq * 4 + 3][p] = pk_bf16(v0.w, v1.w);
    }
    __syncthreads();

    const int wave = t >> 6, lane = t & 63;
    const int ml = lane & 15;             // m-offset (QK^T D col) / h (PV D col)
    const int g  = lane >> 4;             // k-group
    const int m0w = m0b + wave * 16;

    // ---- Q fragment (B operand), 0.25 scale folded; k 16..31 zero ----
    FragU qf;
    if (g < 2) {
        const float* qr = q + (size_t)b * 524288
                            + (size_t)(m0w + ml) * 512 + c * 16 + g * 8;
        float4 a  = *(const float4*)qr;
        float4 bq = *(const float4*)(qr + 4);
        qf.u[0] = pk_bf16(a.x * 0.25f, a.y * 0.25f);
        qf.u[1] = pk_bf16(a.z * 0.25f, a.w * 0.25f);
        qf.u[2] = pk_bf16(bq.x * 0.25f, bq.y * 0.25f);
        qf.u[3] = pk_bf16(bq.z * 0.25f, bq.w * 0.25f);
    } else {
        qf.u = (u32x4){0, 0, 0, 0};
    }

    const f32x4 zero4 = {0.f, 0.f, 0.f, 0.f};

    // ---- pass 1: row sums ----
    float rs = 0.f;
#pragma unroll 1
    for (int nt = 0; nt < 64; ++nt) {
        FragU ka;
        if (lane < 32) ka.u = *(const u32x4*)&ksF[nt * 128 + lane * 4];
        else           ka.u = (u32x4){0, 0, 0, 0};
        f32x4 st = __builtin_amdgcn_mfma_f32_16x16x32_bf16(ka.s, qf.s, zero4, 0, 0, 0);
        rs += (__expf(st[0]) + __expf(st[1])) + (__expf(st[2]) + __expf(st[3]));
    }
    rs += __shfl_xor(rs, 16);
    rs += __shfl_xor(rs, 32);
    const float inv = 1.0f / rs;

    // ---- pass 2: weights store + PV ----
    f32x4 acc = zero4;
    float* wrow = wts + (size_t)cb * 1048576 + (size_t)(m0w + ml) * 1024;
#pragma unroll 1
    for (int ntp = 0; ntp < 32; ++ntp) {
#pragma unroll
        for (int sub = 0; sub < 2; ++sub) {
            const int nt = ntp * 2 + sub;
            FragU ka;
            if (lane < 32) ka.u = *(const u32x4*)&ksF[nt * 128 + lane * 4];
            else           ka.u = (u32x4){0, 0, 0, 0};
            f32x4 st = __builtin_amdgcn_mfma_f32_16x16x32_bf16(ka.s, qf.s, zero4, 0, 0, 0);
            float w0 = __expf(st[0]) * inv;
            float w1 = __expf(st[1]) * inv;
            float w2 = __expf(st[2]) * inv;
            float w3 = __expf(st[3]) * inv;
            // weights: reg r -> n = nt*16 + g*4 + r, row m = m0w+ml (nontemporal)
            f32x4 w4 = {w0, w1, w2, w3};
            __builtin_nontemporal_store(
                w4, reinterpret_cast<f32x4*>(wrow + nt * 16 + g * 4));
            // P tile to per-wave LDS: [m=ml][n-pair = sub*8 + g*2 + {0,1}]
            unsigned* pb = &pbuf[wave][ml][sub * 8 + g * 2];
            pb[0] = pk_bf16(w0, w1);
            pb[1] = pk_bf16(w2, w3);
        }
        // PV over this 32-n block (same-wave LDS: in-order, compiler waits)
        FragU pa, vf;
        pa.u = *(const u32x4*)&pbuf[wave][ml][g * 4];           // row m=ml, k pairs
        vf.u = *(const u32x4*)&vsT[ml][ntp * 16 + g * 4];       // col h=ml, k pairs
        acc = __builtin_amdgcn_mfma_f32_16x16x32_bf16(pa.s, vf.s, acc, 0, 0, 0);
    }

    // ---- att write (scrambled): D2 row = m-offset g*4+r, col = h = ml ----
    const int b2 = c >> 4;
#pragma unroll
    for (int r = 0; r < 4; ++r) {
        const int m  = m0w + g * 4 + r;
        const int m2 = (c & 15) * 64 + (m >> 4);
        const int d2 = (m & 15) * 32 + b * 16 + ml;
        att[((size_t)b2 * 1024 + m2) * 512 + d2] = acc[r];
    }
}

// ---------------------------------------------------------------------------
extern "C" void kernel_launch(void* const* d_in, const int* in_sizes, int n_in,
                              void* d_out, int out_size, void* d_ws, size_t ws_size,
                              hipStream_t stream)
{
    (void)in_sizes; (void)n_in; (void)out_size; (void)ws_size;
    const float* Q  = (const float*)d_in[0];
    const float* K  = (const float*)d_in[1];
    const float* V  = (const float*)d_in[2];
    const float* Wq = (const float*)d_in[3];
    const float* Wk = (const float*)d_in[4];
    const float* Wv = (const float*)d_in[5];
    const float* Wo = (const float*)d_in[6];

    float* out = (float*)d_out;
    float* wts = out + 1048576;            // weights output region (64M floats)

    float* ws  = (float*)d_ws;
    float* q   = ws;                        // 1M floats
    float* k   = ws + (1u << 20);           // 1M
    float* v   = ws + 2 * (1u << 20);       // 1M
    float* att = ws + 3 * (1u << 20);       // 1M (scrambled out_pre)

    proj3_kernel<<<dim3(8, 16, 3), 256, 0, stream>>>(Q, K, V, Wq, Wk, Wv, q, k, v);
    attn_mfma_kernel<<<512, 512, 0, stream>>>(q, k, v, wts, att);
    outproj_kernel<<<dim3(8, 16, 1), 256, 0, stream>>>(att, Wo, out);
}

// Round 16
// 103.272 us; speedup vs baseline: 1.3750x; 1.3750x over previous
//
#include <hip/hip_runtime.h>
#include <cstdint>
#include <cstddef>

// B=2, S=1024, D=512, NH=16 (chunk width), C=32 chunks.
// weights (C,B,S,S) fp32 = 256 MiB written once (fused, never re-read).
// out_pre scramble: (c,b,m,h) -> [c>>4][(c&15)*64 + (m>>4)][(m&15)*32 + b*16 + h]

typedef __attribute__((ext_vector_type(8)))  short    short8;   // 8 bf16 (4 VGPR)
typedef __attribute__((ext_vector_type(4)))  float    f32x4;    // 16x16 MFMA C/D
typedef __attribute__((ext_vector_type(4)))  unsigned u32x4;

union FragU { u32x4 u; short8 s; };

// bf16 round-to-nearest-even pack of two floats into one u32 (lo=a, hi=b)
__device__ __forceinline__ unsigned pk_bf16(float a, float b) {
    unsigned ua = __float_as_uint(a), ub = __float_as_uint(b);
    ua = (ua + 0x7fffu + ((ua >> 16) & 1u)) >> 16;
    ub = (ub + 0x7fffu + ((ub >> 16) & 1u)) >> 16;
    return ua | (ub << 16);
}

// ---------------------------------------------------------------------------
// MFMA NT GEMM v2: P[M][512] = bf16(X) * bf16(W)^T, tile 128m x 64n.
// (KEPT from R15 to isolate it from the nt-store variable.)
// Wave owns 32 rows x 64 cols = 2 A-frags + 4 B-frags -> 6 ds_read_b128 per
// 8 MFMA. 4 K-stages of 128. Fragment discipline verified (R12/R13):
// A row=lane&15, k=(lane>>4)*8+idx; B identical; D col=lane&15,
// row=(lane>>4)*4+reg. LDS 51KB -> 2 blocks/CU. VGPR ~100 < 128 cap.
// ---------------------------------------------------------------------------
__device__ __forceinline__ void gemm_nt_mfma_body(const float* __restrict__ X,
                                                  const float* __restrict__ W,
                                                  float* __restrict__ P)
{
    __shared__ unsigned Xs[128 * 17 * 4];  // 34 KB
    __shared__ unsigned Ws[64 * 17 * 4];   // 17 KB
    const int t  = threadIdx.x;
    const int m0 = blockIdx.y << 7;        // 128-row tile
    const int n0 = blockIdx.x << 6;        // 64-col tile
    const int wave = t >> 6, lane = t & 63;
    const int ml = lane & 15;              // A row / B col within 16
    const int g  = lane >> 4;              // k-group (0..3)

    f32x4 acc[2][4] = {{{0,0,0,0},{0,0,0,0},{0,0,0,0},{0,0,0,0}},
                       {{0,0,0,0},{0,0,0,0},{0,0,0,0},{0,0,0,0}}};

#pragma unroll 1
    for (int st = 0; st < 4; ++st) {
        if (st) __syncthreads();           // prior compute done before restage
        // ---- stage X: 128 rows x 16 kf (kf fastest; 8 reps) ----
#pragma unroll
        for (int rep = 0; rep < 8; ++rep) {
            int f  = rep * 256 + t;
            int kf = f & 15, r = f >> 4;
            const float* xr = X + (size_t)(m0 + r) * 512 + st * 128 + kf * 8;
            float4 a = *(const float4*)xr;
            float4 b = *(const float4*)(xr + 4);
            unsigned* dx = &Xs[(r * 17 + kf) * 4];
            dx[0] = pk_bf16(a.x, a.y); dx[1] = pk_bf16(a.z, a.w);
            dx[2] = pk_bf16(b.x, b.y); dx[3] = pk_bf16(b.z, b.w);
        }
        // ---- stage W: 64 rows x 16 kf (4 reps) ----
#pragma unroll
        for (int rep = 0; rep < 4; ++rep) {
            int f  = rep * 256 + t;
            int kf = f & 15, r = f >> 4;
            const float* wr = W + (size_t)(n0 + r) * 512 + st * 128 + kf * 8;
            float4 c = *(const float4*)wr;
            float4 d = *(const float4*)(wr + 4);
            unsigned* dw = &Ws[(r * 17 + kf) * 4];
            dw[0] = pk_bf16(c.x, c.y); dw[1] = pk_bf16(c.z, c.w);
            dw[2] = pk_bf16(d.x, d.y); dw[3] = pk_bf16(d.z, d.w);
        }
        __syncthreads();
        // ---- compute: 4 k-steps of 32 ----
#pragma unroll
        for (int ks = 0; ks < 4; ++ks) {
            const int kf = ks * 4 + g;
            FragU a0, a1;
            a0.u = *(const u32x4*)&Xs[((wave * 32 + ml) * 17 + kf) * 4];
            a1.u = *(const u32x4*)&Xs[((wave * 32 + 16 + ml) * 17 + kf) * 4];
#pragma unroll
            for (int nf = 0; nf < 4; ++nf) {
                FragU bw;
                bw.u = *(const u32x4*)&Ws[((nf * 16 + ml) * 17 + kf) * 4];
                acc[0][nf] = __builtin_amdgcn_mfma_f32_16x16x32_bf16(
                    a0.s, bw.s, acc[0][nf], 0, 0, 0);
                acc[1][nf] = __builtin_amdgcn_mfma_f32_16x16x32_bf16(
                    a1.s, bw.s, acc[1][nf], 0, 0, 0);
            }
        }
    }
    // ---- store: row = wave*32 + af*16 + g*4 + r, col = nf*16 + ml ----
#pragma unroll
    for (int af = 0; af < 2; ++af)
#pragma unroll
        for (int nf = 0; nf < 4; ++nf)
#pragma unroll
            for (int r = 0; r < 4; ++r) {
                const int m = m0 + wave * 32 + af * 16 + g * 4 + r;
                P[(size_t)m * 512 + n0 + nf * 16 + ml] = acc[af][nf][r];
            }
}

__global__ __launch_bounds__(256, 2) void proj3_kernel(
    const float* __restrict__ Q, const float* __restrict__ K, const float* __restrict__ V,
    const float* __restrict__ Wq, const float* __restrict__ Wk, const float* __restrict__ Wv,
    float* __restrict__ q, float* __restrict__ k, float* __restrict__ v)
{
    const float* X; const float* W; float* P;
    if (blockIdx.z == 0)      { X = Q; W = Wq; P = q; }
    else if (blockIdx.z == 1) { X = K; W = Wk; P = k; }
    else                      { X = V; W = Wv; P = v; }
    gemm_nt_mfma_body(X, W, P);
}

__global__ __launch_bounds__(256, 2) void outproj_kernel(
    const float* __restrict__ att, const float* __restrict__ Wo, float* __restrict__ out)
{
    gemm_nt_mfma_body(att, Wo, out);
}

// ---------------------------------------------------------------------------
// v12 MFMA attention — EXACT R14 state (105.3us): plain float4 weights
// stores (nontemporal REVERTED: prime suspect for the R15 +37us regression).
// 8 waves/block, 512 threads, LDS 73.1KB -> 2 blocks/CU -> 4 waves/SIMD.
// ---------------------------------------------------------------------------
__global__ __launch_bounds__(512)
void attn_mfma_kernel(
    const float* __restrict__ q, const float* __restrict__ k, const float* __restrict__ v,
    float* __restrict__ wts, float* __restrict__ att)
{
    __shared__ unsigned ksF[64 * 128];    // [nt][(n&15)+16g][4] bf16-pair frags
    __shared__ unsigned vsT[16][514];     // [h][n-pair] bf16x2 (+pad, 0-conflict)
    __shared__ unsigned pbuf[8][16][18];  // per-wave P tile [m][n-pair], padded

    const int t     = threadIdx.x;
    const int bid   = blockIdx.x;         // 512 blocks
    const int strip = bid & 7;            // 8 strips of 128 m-rows
    const int cb    = bid >> 3;           // c*2 + b
    const int b     = cb & 1;
    const int c     = cb >> 1;
    const int m0b   = strip << 7;

    const float* kb = k + (size_t)b * 524288 + c * 16;
    const float* vb = v + (size_t)b * 524288 + c * 16;

    // ---- stage K as A-fragments: tasks (n 0..1023, g 0..1) ----
#pragma unroll
    for (int rep = 0; rep < 4; ++rep) {
        int f = rep * 512 + t;            // 0..2047
        int n = f >> 1, gg = f & 1;
        const float* kr = kb + (size_t)n * 512 + gg * 8;
        float4 a  = *(const float4*)kr;
        float4 bq = *(const float4*)(kr + 4);
        unsigned* dst = &ksF[(n >> 4) * 128 + ((n & 15) + (gg << 4)) * 4];
        dst[0] = pk_bf16(a.x, a.y);
        dst[1] = pk_bf16(a.z, a.w);
        dst[2] = pk_bf16(bq.x, bq.y);
        dst[3] = pk_bf16(bq.z, bq.w);
    }
    // ---- stage V as [h][n-pair] bf16 pairs ----
#pragma unroll
    for (int rep = 0; rep < 4; ++rep) {
        int f = rep * 512 + t;            // p(0..511) x hq(0..3)
        int p = f >> 2, hq = f & 3;
        float4 v0 = *(const float4*)(vb + (size_t)(2 * p)     * 512 + hq * 4);
        float4 v1 = *(const float4*)(vb + (size_t)(2 * p + 1) * 512 + hq * 4);
        vsT[hq * 4 + 0][p] = pk_bf16(v0.x, v1.x);
        vsT[hq * 4 + 1][p] = pk_bf16(v0.y, v1.y);
        vsT[hq * 4 + 2][p] = pk_bf16(v0.z, v1.z);
        vsT[hq * 4 + 3][p] = pk_bf16(v0.w, v1.w);
    }
    __syncthreads();

    const int wave = t >> 6, lane = t & 63;
    const int ml = lane & 15;             // m-offset (QK^T D col) / h (PV D col)
    const int g  = lane >> 4;             // k-group
    const int m0w = m0b + wave * 16;

    // ---- Q fragment (B operand), 0.25 scale folded; k 16..31 zero ----
    FragU qf;
    if (g < 2) {
        const float* qr = q + (size_t)b * 524288
                            + (size_t)(m0w + ml) * 512 + c * 16 + g * 8;
        float4 a  = *(const float4*)qr;
        float4 bq = *(const float4*)(qr + 4);
        qf.u[0] = pk_bf16(a.x * 0.25f, a.y * 0.25f);
        qf.u[1] = pk_bf16(a.z * 0.25f, a.w * 0.25f);
        qf.u[2] = pk_bf16(bq.x * 0.25f, bq.y * 0.25f);
        qf.u[3] = pk_bf16(bq.z * 0.25f, bq.w * 0.25f);
    } else {
        qf.u = (u32x4){0, 0, 0, 0};
    }

    const f32x4 zero4 = {0.f, 0.f, 0.f, 0.f};

    // ---- pass 1: row sums ----
    float rs = 0.f;
#pragma unroll 1
    for (int nt = 0; nt < 64; ++nt) {
        FragU ka;
        if (lane < 32) ka.u = *(const u32x4*)&ksF[nt * 128 + lane * 4];
        else           ka.u = (u32x4){0, 0, 0, 0};
        f32x4 st = __builtin_amdgcn_mfma_f32_16x16x32_bf16(ka.s, qf.s, zero4, 0, 0, 0);
        rs += (__expf(st[0]) + __expf(st[1])) + (__expf(st[2]) + __expf(st[3]));
    }
    rs += __shfl_xor(rs, 16);
    rs += __shfl_xor(rs, 32);
    const float inv = 1.0f / rs;

    // ---- pass 2: weights store + PV ----
    f32x4 acc = zero4;
    float* wrow = wts + (size_t)cb * 1048576 + (size_t)(m0w + ml) * 1024;
#pragma unroll 1
    for (int ntp = 0; ntp < 32; ++ntp) {
#pragma unroll
        for (int sub = 0; sub < 2; ++sub) {
            const int nt = ntp * 2 + sub;
            FragU ka;
            if (lane < 32) ka.u = *(const u32x4*)&ksF[nt * 128 + lane * 4];
            else           ka.u = (u32x4){0, 0, 0, 0};
            f32x4 st = __builtin_amdgcn_mfma_f32_16x16x32_bf16(ka.s, qf.s, zero4, 0, 0, 0);
            float w0 = __expf(st[0]) * inv;
            float w1 = __expf(st[1]) * inv;
            float w2 = __expf(st[2]) * inv;
            float w3 = __expf(st[3]) * inv;
            // weights: reg r -> n = nt*16 + g*4 + r, row m = m0w+ml
            *(float4*)(wrow + nt * 16 + g * 4) = make_float4(w0, w1, w2, w3);
            // P tile to per-wave LDS: [m=ml][n-pair = sub*8 + g*2 + {0,1}]
            unsigned* pb = &pbuf[wave][ml][sub * 8 + g * 2];
            pb[0] = pk_bf16(w0, w1);
            pb[1] = pk_bf16(w2, w3);
        }
        // PV over this 32-n block (same-wave LDS: in-order, compiler waits)
        FragU pa, vf;
        pa.u = *(const u32x4*)&pbuf[wave][ml][g * 4];           // row m=ml, k pairs
        vf.u = *(const u32x4*)&vsT[ml][ntp * 16 + g * 4];       // col h=ml, k pairs
        acc = __builtin_amdgcn_mfma_f32_16x16x32_bf16(pa.s, vf.s, acc, 0, 0, 0);
    }

    // ---- att write (scrambled): D2 row = m-offset g*4+r, col = h = ml ----
    const int b2 = c >> 4;
#pragma unroll
    for (int r = 0; r < 4; ++r) {
        const int m  = m0w + g * 4 + r;
        const int m2 = (c & 15) * 64 + (m >> 4);
        const int d2 = (m & 15) * 32 + b * 16 + ml;
        att[((size_t)b2 * 1024 + m2) * 512 + d2] = acc[r];
    }
}

// ---------------------------------------------------------------------------
extern "C" void kernel_launch(void* const* d_in, const int* in_sizes, int n_in,
                              void* d_out, int out_size, void* d_ws, size_t ws_size,
                              hipStream_t stream)
{
    (void)in_sizes; (void)n_in; (void)out_size; (void)ws_size;
    const float* Q  = (const float*)d_in[0];
    const float* K  = (const float*)d_in[1];
    const float* V  = (const float*)d_in[2];
    const float* Wq = (const float*)d_in[3];
    const float* Wk = (const float*)d_in[4];
    const float* Wv = (const float*)d_in[5];
    const float* Wo = (const float*)d_in[6];

    float* out = (float*)d_out;
    float* wts = out + 1048576;            // weights output region (64M floats)

    float* ws  = (float*)d_ws;
    float* q   = ws;                        // 1M floats
    float* k   = ws + (1u << 20);           // 1M
    float* v   = ws + 2 * (1u << 20);       // 1M
    float* att = ws + 3 * (1u << 20);       // 1M (scrambled out_pre)

    proj3_kernel<<<dim3(8, 16, 3), 256, 0, stream>>>(Q, K, V, Wq, Wk, Wv, q, k, v);
    attn_mfma_kernel<<<512, 512, 0, stream>>>(q, k, v, wts, att);
    outproj_kernel<<<dim3(8, 16, 1), 256, 0, stream>>>(att, Wo, out);
}

// Round 17
// 97.389 us; speedup vs baseline: 1.4581x; 1.0604x over previous
//
#include <hip/hip_runtime.h>
#include <cstdint>
#include <cstddef>

// B=2, S=1024, D=512, NH=16 (chunk width), C=32 chunks.
// weights (C,B,S,S) fp32 = 256 MiB written once (fused, never re-read).
// out_pre scramble: (c,b,m,h) -> [c>>4][(c&15)*64 + (m>>4)][(m&15)*32 + b*16 + h]
// R17: q,k,v flow between kernels as bf16 (producer-side conversion).
//  - proj3 stores bf16 u16; Wq staged with 0.25 folded in (exact exp shift).
//  - attn: K-staging & Q-frag = plain 16B copies (row-major bf16 IS the
//    fragment layout); V-staging = 8B loads + bitmerge. No pk_bf16 left.
//  - Bit-identical math to R16 -> absmax must stay 2.9297e-3.

typedef __attribute__((ext_vector_type(8)))  short    short8;   // 8 bf16 (4 VGPR)
typedef __attribute__((ext_vector_type(4)))  float    f32x4;    // 16x16 MFMA C/D
typedef __attribute__((ext_vector_type(4)))  unsigned u32x4;

union FragU { u32x4 u; short8 s; };

// bf16 round-to-nearest-even pack of two floats into one u32 (lo=a, hi=b)
__device__ __forceinline__ unsigned pk_bf16(float a, float b) {
    unsigned ua = __float_as_uint(a), ub = __float_as_uint(b);
    ua = (ua + 0x7fffu + ((ua >> 16) & 1u)) >> 16;
    ub = (ub + 0x7fffu + ((ub >> 16) & 1u)) >> 16;
    return ua | (ub << 16);
}
__device__ __forceinline__ unsigned short bf16_1(float a) {
    unsigned ua = __float_as_uint(a);
    return (unsigned short)((ua + 0x7fffu + ((ua >> 16) & 1u)) >> 16);
}

// ---------------------------------------------------------------------------
// MFMA NT GEMM (tile 128m x 64n, verified fragment discipline R12-R16).
// BF16OUT: store bf16 u16 (producer-side conversion for q/k/v).
// wscale: folded into staged W values (0.25 for Wq -> q pre-scaled, exact).
// ---------------------------------------------------------------------------
template <bool BF16OUT>
__device__ __forceinline__ void gemm_nt_mfma_body(const float* __restrict__ X,
                                                  const float* __restrict__ W,
                                                  void* __restrict__ Pout,
                                                  float wscale)
{
    __shared__ unsigned Xs[128 * 17 * 4];  // 34 KB
    __shared__ unsigned Ws[64 * 17 * 4];   // 17 KB
    const int t  = threadIdx.x;
    const int m0 = blockIdx.y << 7;        // 128-row tile
    const int n0 = blockIdx.x << 6;        // 64-col tile
    const int wave = t >> 6, lane = t & 63;
    const int ml = lane & 15;              // A row / B col within 16
    const int g  = lane >> 4;              // k-group (0..3)

    f32x4 acc[2][4] = {{{0,0,0,0},{0,0,0,0},{0,0,0,0},{0,0,0,0}},
                       {{0,0,0,0},{0,0,0,0},{0,0,0,0},{0,0,0,0}}};

#pragma unroll 1
    for (int st = 0; st < 4; ++st) {
        if (st) __syncthreads();           // prior compute done before restage
        // ---- stage X: 128 rows x 16 kf (kf fastest; 8 reps) ----
#pragma unroll
        for (int rep = 0; rep < 8; ++rep) {
            int f  = rep * 256 + t;
            int kf = f & 15, r = f >> 4;
            const float* xr = X + (size_t)(m0 + r) * 512 + st * 128 + kf * 8;
            float4 a = *(const float4*)xr;
            float4 b = *(const float4*)(xr + 4);
            unsigned* dx = &Xs[(r * 17 + kf) * 4];
            dx[0] = pk_bf16(a.x, a.y); dx[1] = pk_bf16(a.z, a.w);
            dx[2] = pk_bf16(b.x, b.y); dx[3] = pk_bf16(b.z, b.w);
        }
        // ---- stage W: 64 rows x 16 kf (4 reps), wscale folded ----
#pragma unroll
        for (int rep = 0; rep < 4; ++rep) {
            int f  = rep * 256 + t;
            int kf = f & 15, r = f >> 4;
            const float* wr = W + (size_t)(n0 + r) * 512 + st * 128 + kf * 8;
            float4 c = *(const float4*)wr;
            float4 d = *(const float4*)(wr + 4);
            unsigned* dw = &Ws[(r * 17 + kf) * 4];
            dw[0] = pk_bf16(c.x * wscale, c.y * wscale);
            dw[1] = pk_bf16(c.z * wscale, c.w * wscale);
            dw[2] = pk_bf16(d.x * wscale, d.y * wscale);
            dw[3] = pk_bf16(d.z * wscale, d.w * wscale);
        }
        __syncthreads();
        // ---- compute: 4 k-steps of 32 ----
#pragma unroll
        for (int ks = 0; ks < 4; ++ks) {
            const int kf = ks * 4 + g;
            FragU a0, a1;
            a0.u = *(const u32x4*)&Xs[((wave * 32 + ml) * 17 + kf) * 4];
            a1.u = *(const u32x4*)&Xs[((wave * 32 + 16 + ml) * 17 + kf) * 4];
#pragma unroll
            for (int nf = 0; nf < 4; ++nf) {
                FragU bw;
                bw.u = *(const u32x4*)&Ws[((nf * 16 + ml) * 17 + kf) * 4];
                acc[0][nf] = __builtin_amdgcn_mfma_f32_16x16x32_bf16(
                    a0.s, bw.s, acc[0][nf], 0, 0, 0);
                acc[1][nf] = __builtin_amdgcn_mfma_f32_16x16x32_bf16(
                    a1.s, bw.s, acc[1][nf], 0, 0, 0);
            }
        }
    }
    // ---- store: row = wave*32 + af*16 + g*4 + r, col = nf*16 + ml ----
#pragma unroll
    for (int af = 0; af < 2; ++af)
#pragma unroll
        for (int nf = 0; nf < 4; ++nf)
#pragma unroll
            for (int r = 0; r < 4; ++r) {
                const int m = m0 + wave * 32 + af * 16 + g * 4 + r;
                const size_t idx = (size_t)m * 512 + n0 + nf * 16 + ml;
                if (BF16OUT)
                    ((unsigned short*)Pout)[idx] = bf16_1(acc[af][nf][r]);
                else
                    ((float*)Pout)[idx] = acc[af][nf][r];
            }
}

__global__ __launch_bounds__(256, 2) void proj3_kernel(
    const float* __restrict__ Q, const float* __restrict__ K, const float* __restrict__ V,
    const float* __restrict__ Wq, const float* __restrict__ Wk, const float* __restrict__ Wv,
    unsigned short* __restrict__ q, unsigned short* __restrict__ k,
    unsigned short* __restrict__ v)
{
    const float* X; const float* W; unsigned short* P; float ws;
    if (blockIdx.z == 0)      { X = Q; W = Wq; P = q; ws = 0.25f; }
    else if (blockIdx.z == 1) { X = K; W = Wk; P = k; ws = 1.0f; }
    else                      { X = V; W = Wv; P = v; ws = 1.0f; }
    gemm_nt_mfma_body<true>(X, W, P, ws);
}

__global__ __launch_bounds__(256, 2) void outproj_kernel(
    const float* __restrict__ att, const float* __restrict__ Wo, float* __restrict__ out)
{
    gemm_nt_mfma_body<false>(att, Wo, out, 1.0f);
}

// ---------------------------------------------------------------------------
// v13 MFMA attention: R14/R16 structure (103.3us) with bf16 producers.
// K-staging & Q-frag: direct 16B copies (bf16 row-major == fragment layout).
// V-staging: 2x8B loads + bitmerge into [h][n-pair]. Q pre-scaled by 0.25.
// 8 waves/block, 512 threads, LDS 73.1KB -> 2 blocks/CU -> 4 waves/SIMD.
// ---------------------------------------------------------------------------
__global__ __launch_bounds__(512)
void attn_mfma_kernel(
    const unsigned short* __restrict__ q, const unsigned short* __restrict__ k,
    const unsigned short* __restrict__ v,
    float* __restrict__ wts, float* __restrict__ att)
{
    __shared__ unsigned ksF[64 * 128];    // [nt][(n&15)+16g][4] bf16-pair frags
    __shared__ unsigned vsT[16][514];     // [h][n-pair] bf16x2 (+pad, 0-conflict)
    __shared__ unsigned pbuf[8][16][18];  // per-wave P tile [m][n-pair], padded

    const int t     = threadIdx.x;
    const int bid   = blockIdx.x;         // 512 blocks
    const int strip = bid & 7;            // 8 strips of 128 m-rows
    const int cb    = bid >> 3;           // c*2 + b
    const int b     = cb & 1;
    const int c     = cb >> 1;
    const int m0b   = strip << 7;

    const unsigned short* kb = k + (size_t)b * 524288 + c * 16;
    const unsigned short* vb = v + (size_t)b * 524288 + c * 16;

    // ---- stage K as A-fragments: direct 16B copies (n 0..1023, g 0..1) ----
#pragma unroll
    for (int rep = 0; rep < 4; ++rep) {
        int f = rep * 512 + t;            // 0..2047
        int n = f >> 1, gg = f & 1;
        u32x4 kv = *(const u32x4*)(kb + (size_t)n * 512 + gg * 8);
        *(u32x4*)&ksF[(n >> 4) * 128 + ((n & 15) + (gg << 4)) * 4] = kv;
    }
    // ---- stage V as [h][n-pair]: 2x8B loads + bitmerge ----
#pragma unroll
    for (int rep = 0; rep < 4; ++rep) {
        int f = rep * 512 + t;            // p(0..511) x hq(0..3)
        int p = f >> 2, hq = f & 3;
        uint2 a  = *(const uint2*)(vb + (size_t)(2 * p)     * 512 + hq * 4);
        uint2 bb = *(const uint2*)(vb + (size_t)(2 * p + 1) * 512 + hq * 4);
        vsT[hq * 4 + 0][p] = (a.x & 0xffffu) | (bb.x << 16);
        vsT[hq * 4 + 1][p] = (a.x >> 16) | (bb.x & 0xffff0000u);
        vsT[hq * 4 + 2][p] = (a.y & 0xffffu) | (bb.y << 16);
        vsT[hq * 4 + 3][p] = (a.y >> 16) | (bb.y & 0xffff0000u);
    }
    __syncthreads();

    const int wave = t >> 6, lane = t & 63;
    const int ml = lane & 15;             // m-offset (QK^T D col) / h (PV D col)
    const int g  = lane >> 4;             // k-group
    const int m0w = m0b + wave * 16;

    // ---- Q fragment (B operand): direct 16B copy (0.25 pre-folded) ----
    FragU qf;
    if (g < 2) {
        qf.u = *(const u32x4*)(q + (size_t)b * 524288
                                 + (size_t)(m0w + ml) * 512 + c * 16 + g * 8);
    } else {
        qf.u = (u32x4){0, 0, 0, 0};
    }

    const f32x4 zero4 = {0.f, 0.f, 0.f, 0.f};

    // ---- pass 1: row sums ----
    float rs = 0.f;
#pragma unroll 1
    for (int nt = 0; nt < 64; ++nt) {
        FragU ka;
        if (lane < 32) ka.u = *(const u32x4*)&ksF[nt * 128 + lane * 4];
        else           ka.u = (u32x4){0, 0, 0, 0};
        f32x4 st = __builtin_amdgcn_mfma_f32_16x16x32_bf16(ka.s, qf.s, zero4, 0, 0, 0);
        rs += (__expf(st[0]) + __expf(st[1])) + (__expf(st[2]) + __expf(st[3]));
    }
    rs += __shfl_xor(rs, 16);
    rs += __shfl_xor(rs, 32);
    const float inv = 1.0f / rs;

    // ---- pass 2: weights store + PV ----
    f32x4 acc = zero4;
    float* wrow = wts + (size_t)cb * 1048576 + (size_t)(m0w + ml) * 1024;
#pragma unroll 1
    for (int ntp = 0; ntp < 32; ++ntp) {
#pragma unroll
        for (int sub = 0; sub < 2; ++sub) {
            const int nt = ntp * 2 + sub;
            FragU ka;
            if (lane < 32) ka.u = *(const u32x4*)&ksF[nt * 128 + lane * 4];
            else           ka.u = (u32x4){0, 0, 0, 0};
            f32x4 st = __builtin_amdgcn_mfma_f32_16x16x32_bf16(ka.s, qf.s, zero4, 0, 0, 0);
            float w0 = __expf(st[0]) * inv;
            float w1 = __expf(st[1]) * inv;
            float w2 = __expf(st[2]) * inv;
            float w3 = __expf(st[3]) * inv;
            // weights: reg r -> n = nt*16 + g*4 + r, row m = m0w+ml
            *(float4*)(wrow + nt * 16 + g * 4) = make_float4(w0, w1, w2, w3);
            // P tile to per-wave LDS: [m=ml][n-pair = sub*8 + g*2 + {0,1}]
            unsigned* pb = &pbuf[wave][ml][sub * 8 + g * 2];
            pb[0] = pk_bf16(w0, w1);
            pb[1] = pk_bf16(w2, w3);
        }
        // PV over this 32-n block (same-wave LDS: in-order, compiler waits)
        FragU pa, vf;
        pa.u = *(const u32x4*)&pbuf[wave][ml][g * 4];           // row m=ml, k pairs
        vf.u = *(const u32x4*)&vsT[ml][ntp * 16 + g * 4];       // col h=ml, k pairs
        acc = __builtin_amdgcn_mfma_f32_16x16x32_bf16(pa.s, vf.s, acc, 0, 0, 0);
    }

    // ---- att write (scrambled): D2 row = m-offset g*4+r, col = h = ml ----
    const int b2 = c >> 4;
#pragma unroll
    for (int r = 0; r < 4; ++r) {
        const int m  = m0w + g * 4 + r;
        const int m2 = (c & 15) * 64 + (m >> 4);
        const int d2 = (m & 15) * 32 + b * 16 + ml;
        att[((size_t)b2 * 1024 + m2) * 512 + d2] = acc[r];
    }
}

// ---------------------------------------------------------------------------
extern "C" void kernel_launch(void* const* d_in, const int* in_sizes, int n_in,
                              void* d_out, int out_size, void* d_ws, size_t ws_size,
                              hipStream_t stream)
{
    (void)in_sizes; (void)n_in; (void)out_size; (void)ws_size;
    const float* Q  = (const float*)d_in[0];
    const float* K  = (const float*)d_in[1];
    const float* V  = (const float*)d_in[2];
    const float* Wq = (const float*)d_in[3];
    const float* Wk = (const float*)d_in[4];
    const float* Wv = (const float*)d_in[5];
    const float* Wo = (const float*)d_in[6];

    float* out = (float*)d_out;
    float* wts = out + 1048576;            // weights output region (64M floats)

    float* ws  = (float*)d_ws;
    unsigned short* q16 = (unsigned short*)ws;                   // 2 MB
    unsigned short* k16 = (unsigned short*)(ws + (1u << 19));    // 2 MB
    unsigned short* v16 = (unsigned short*)(ws + (1u << 20));    // 2 MB
    float* att = ws + 2 * (1u << 20);                            // 4 MB fp32

    proj3_kernel<<<dim3(8, 16, 3), 256, 0, stream>>>(Q, K, V, Wq, Wk, Wv,
                                                     q16, k16, v16);
    attn_mfma_kernel<<<512, 512, 0, stream>>>(q16, k16, v16, wts, att);
    outproj_kernel<<<dim3(8, 16, 1), 256, 0, stream>>>(att, Wo, out);
}